// Round 10
// baseline (574.162 us; speedup 1.0000x reference)
//
#include <hip/hip_runtime.h>
#include <hip/hip_bf16.h>

typedef __hip_bfloat16 bf16;
typedef __attribute__((ext_vector_type(8))) short short8;
typedef __attribute__((ext_vector_type(4))) float f32x4;

#define NTOKENS 131072   // 2*4*128*128
#define MFMA __builtin_amdgcn_mfma_f32_16x16x32_bf16

// ---- workspace layout (bytes) ----
static constexpr size_t A_OFF    = 0;                                  // xw bf16 [131072][192]
static constexpr size_t Q_OFF    = A_OFF   + (size_t)NTOKENS*192*2;    // qkv bf16 [131072][576]
static constexpr size_t O_OFF    = Q_OFF   + (size_t)NTOKENS*576*2;    // x_out bf16 [131072][384]
static constexpr size_t POS_OFF  = O_OFF   + (size_t)NTOKENS*384*2;    // pos f32 [128][192]
static constexpr size_t PB_OFF   = POS_OFF + (size_t)128*192*4;        // pos@Wm^T+b f32 [128][576]
static constexpr size_t RPBF_OFF = PB_OFF  + (size_t)128*576*4;        // rpbF bf16 [6][32][128][4]
static constexpr size_t MSKF_OFF = RPBF_OFF+ (size_t)6*128*128*2;      // mskF bf16 [512][32][128][4]
static constexpr size_t WB_OFF   = MSKF_OFF+ (size_t)512*128*128*2;    // bf16 weights
static constexpr size_t WQS_E = 0, WQM_E = 110592, WPR_E = 221184,
                        W11_E = 294912, W12_E = 368640, W2_E = 442368, WTOT = 516096;

__device__ __forceinline__ float u2f(unsigned int ubits) {
    union { unsigned int i; float f; } c; c.i = ubits << 16; return c.f;
}
__device__ __forceinline__ unsigned pkbf(float a, float b) {
    unsigned ua = (unsigned)__bfloat16_as_ushort(__float2bfloat16(a));
    unsigned ub = (unsigned)__bfloat16_as_ushort(__float2bfloat16(b));
    return ua | (ub << 16);
}
__device__ __forceinline__ unsigned swz(unsigned b) { return b ^ (((b >> 9) & 1) << 5); }
__device__ __forceinline__ short8 u4s8(uint4 v) { union { uint4 u; short8 s; } c; c.u = v; return c.s; }

// async 16B global->LDS (linear dest; callers pre-permute the SOURCE granule)
__device__ __forceinline__ void gl16(const bf16* g, void* l) {
    __builtin_amdgcn_global_load_lds(
        (const __attribute__((address_space(1))) void*)g,
        (__attribute__((address_space(3))) void*)l, 16, 0, 0);
}

// ---------------- weight fp32 -> bf16 ----------------------------------------
__global__ __launch_bounds__(256) void cvtw_kernel(
    const float* __restrict__ a, const float* __restrict__ b, const float* __restrict__ c,
    const float* __restrict__ d, const float* __restrict__ e, const float* __restrict__ f,
    bf16* __restrict__ out) {
    int i = blockIdx.x * 256 + threadIdx.x;
    const float* src; int off;
    if      (i < (int)WQM_E) { src = a; off = (int)WQS_E; }
    else if (i < (int)WPR_E) { src = b; off = (int)WQM_E; }
    else if (i < (int)W11_E) { src = c; off = (int)WPR_E; }
    else if (i < (int)W12_E) { src = d; off = (int)W11_E; }
    else if (i < (int)W2_E)  { src = e; off = (int)W12_E; }
    else if (i < (int)WTOT)  { src = f; off = (int)W2_E; }
    else return;
    out[i] = __float2bfloat16(src[i - off]);
}

// ---------------- pos table (f32) --------------------------------------------
__global__ __launch_bounds__(256) void pos_kernel(float* __restrict__ pos) {
    int idx = blockIdx.x * 256 + threadIdx.x;
    if (idx >= 128 * 192) return;
    int t = idx / 192, c = idx - t * 192;
    int s = t & 63;
    int hh = s >> 3, ww = s & 7;
    const float twopi = 6.2831853071795864f;
    float coord = (c < 96) ? (float)(hh + 1) : (float)(ww + 1);
    coord = coord / (8.0f + 1e-6f) * twopi;
    int f = (c < 96) ? c : c - 96;
    float dimt = powf(10000.0f, (float)(2 * (f >> 1)) / 96.0f);
    float v = coord / dimt;
    pos[idx] = (f & 1) ? cosf(v) : sinf(v);
}

// ---------------- PB[t][n] = pos[t]·Wm[n] + bqm[n]  (f32) --------------------
__global__ __launch_bounds__(256) void pbias_kernel(const float* __restrict__ pos,
                                                    const bf16* __restrict__ Wm,
                                                    const float* __restrict__ bqm,
                                                    float* __restrict__ PB) {
    int idx = blockIdx.x * 256 + threadIdx.x;
    if (idx >= 128 * 576) return;
    int t = idx / 576, n = idx - t * 576;
    const float* pp = pos + t * 192;
    const bf16* wp = Wm + (size_t)n * 192;
    float acc = bqm[n];
    for (int k = 0; k < 192; ++k) acc += pp[k] * __bfloat162float(wp[k]);
    PB[idx] = acc;
}

// ---- rpbF[h][j>>2][i][j&3] = tbl[relidx(i,j)][h]  (fragment-quad layout) ----
__global__ __launch_bounds__(256) void rpbF_kernel(const float* __restrict__ tbl,
                                                   bf16* __restrict__ rpbF) {
    int idx = blockIdx.x * 256 + threadIdx.x;
    if (idx >= 6 * 32 * 128 * 4) return;
    int jr = idx & 3;
    int i = (idx >> 2) & 127;
    int jq = (idx >> 9) & 31;
    int h = idx >> 14;
    int j = jq * 4 + jr;                       // i = query row, j = key col
    int di = i >> 6, hi = (i >> 3) & 7, wi = i & 7;
    int dj = j >> 6, hj = (j >> 3) & 7, wj = j & 7;
    int t = (di - dj + 1) * 225 + (hi - hj + 7) * 15 + (wi - wj + 7);
    rpbF[idx] = __float2bfloat16(tbl[t * 6 + h]);
}

// ---- mskF[w][j>>2][i][j&3] = bf16(mask[w][i][j]); float4-coalesced reads ----
__global__ __launch_bounds__(256) void mskF_kernel(const float* __restrict__ mask,
                                                   bf16* __restrict__ mskF) {
    int idx = blockIdx.x * 256 + threadIdx.x;   // 512*128*32
    int widx = idx >> 12;
    int rem = idx & 4095;
    int i = rem >> 5, jq = rem & 31;
    float4 v = *reinterpret_cast<const float4*>(mask + ((size_t)widx << 14) + i * 128 + jq * 4);
    uint2 o;
    o.x = pkbf(v.x, v.y);
    o.y = pkbf(v.z, v.w);
    *reinterpret_cast<uint2*>(mskF + ((size_t)widx << 14) + (jq * 128 + i) * 4) = o;
}

// ---------------- LayerNorm (PART=1: + roll + window partition) --------------
template <int PART>
__global__ __launch_bounds__(256) void ln_kernel(const float* __restrict__ xin,
                                                 const float* __restrict__ w,
                                                 const float* __restrict__ b,
                                                 bf16* __restrict__ out) {
    int tok = blockIdx.x * 4 + (threadIdx.x >> 6);
    int lane = threadIdx.x & 63;
    const float* xp = xin + (size_t)tok * 192;
    float x0 = xp[lane], x1 = xp[lane + 64], x2 = xp[lane + 128];
    float s = x0 + x1 + x2;
    float ss = x0 * x0 + x1 * x1 + x2 * x2;
    for (int off = 32; off; off >>= 1) {
        s += __shfl_xor(s, off);
        ss += __shfl_xor(ss, off);
    }
    float mean = s * (1.0f / 192.0f);
    float var = ss * (1.0f / 192.0f) - mean * mean;
    float rstd = rsqrtf(var + 1e-5f);
    size_t obase;
    if (PART) {
        int bb = tok >> 16;
        int rem = tok & 65535;
        int d = rem >> 14;
        int hw = rem & 16383;
        int hh = hw >> 7, w2 = hw & 127;
        int sd = (d + 3) & 3;
        int sh = (hh + 124) & 127;
        int sw = (w2 + 124) & 127;
        int win = ((bb * 2 + (sd >> 1)) * 16 + (sh >> 3)) * 16 + (sw >> 3);
        int t = ((sd & 1) << 6) | ((sh & 7) << 3) | (sw & 7);
        obase = ((size_t)win * 128 + t) * 192;
    } else {
        obase = (size_t)tok * 192;
    }
    out[obase + lane]       = __float2bfloat16((x0 - mean) * rstd * w[lane] + b[lane]);
    out[obase + lane + 64]  = __float2bfloat16((x1 - mean) * rstd * w[lane + 64] + b[lane + 64]);
    out[obase + lane + 128] = __float2bfloat16((x2 - mean) * rstd * w[lane + 128] + b[lane + 128]);
}

// ---------------- MFMA GEMM (round-7 structure; BN=192 for modes 2/4) --------
// MODE 2: proj + window-reverse + roll + residual (f32 out). BN=192, nb=1:
//         one block owns the whole N row -> 24 MFMA/wave/ks (3x), per-work
//         LDS traffic 1.8x lower, chunk-phase count 3x lower. LDS 80KB ->
//         exactly 2 blocks/CU (same residency as BN=64).
// MODE 3: fc11+fc12 dual W + gelu-gate (bf16 out stride 384)
// MODE 4: fc2 + residual (f32 out). BN=192 like mode 2.
// MODE 5: dual W, two bf16 outs stride 576 (fused self+mutual qkv);
//         parallel dual epilogue (one barrier, interleaved writes).
template <int MODE, int BIAS>
__global__ __launch_bounds__(256) void mgemm(
    const bf16* __restrict__ Ab, int K, int nb,
    const bf16* __restrict__ W1, const float* __restrict__ B1,
    const bf16* __restrict__ W2, const float* __restrict__ B2,
    const float* __restrict__ resid,
    void* __restrict__ outp, void* __restrict__ outp2) {
    constexpr bool DUAL  = (MODE == 3 || MODE == 5);
    constexpr bool WIDE  = (MODE == 2 || MODE == 4);
    constexpr int  WROWS = WIDE ? 192 : 64;     // W tile rows (=BN)
    constexpr int  WCOL  = WROWS / 2;           // cols per wave-col
    constexpr int  NCB   = WCOL / 16;           // 16-col blocks per wave
    __shared__ __align__(16) unsigned char AsB[2][16384];
    __shared__ __align__(16) unsigned char WsB[2][WROWS * 128];
    __shared__ __align__(16) unsigned char Ws2B[DUAL ? 2 : 1][DUAL ? 8192 : 16];

    int total = gridDim.x;
    int bid = blockIdx.x;
    int lin = (bid & 7) * (total >> 3) + (bid >> 3);
    int mb = lin / nb, nbk = lin - mb * nb;
    int m0 = mb << 7, n0 = nbk * WROWS;
    int tid = threadIdx.x;
    int w = tid >> 6, l = tid & 63;
    int wr = w >> 1, wc = w & 1;
    int lr = l & 15, lg = l >> 4;

    f32x4 acc[4][NCB] = {};
    f32x4 acc2[DUAL ? 4 : 1][DUAL ? 2 : 1] = {};

    auto stage = [&](int buf, int kc) {
        int k0 = kc << 6;
#pragma unroll
        for (int it = 0; it < 4; ++it) {
            int idx = it * 256 + tid;
            int row = idx >> 3, gs = idx & 7;
            int gsrc = gs ^ (((row >> 2) & 1) << 1);
            gl16(Ab + (size_t)(m0 + row) * K + k0 + gsrc * 8, &AsB[buf][idx * 16]);
        }
#pragma unroll
        for (int it = 0; it < WROWS / 32; ++it) {
            int idx = it * 256 + tid;
            int row = idx >> 3, gs = idx & 7;
            int gsrc = gs ^ (((row >> 2) & 1) << 1);
            gl16(W1 + (size_t)(n0 + row) * K + k0 + gsrc * 8, &WsB[buf][idx * 16]);
            if (DUAL)
                gl16(W2 + (size_t)(n0 + row) * K + k0 + gsrc * 8, &Ws2B[buf][idx * 16]);
        }
    };

    int nK = K >> 6;
    stage(0, 0);
    __syncthreads();
    for (int kc = 0; kc < nK; ++kc) {
        int cur = kc & 1;
        if (kc + 1 < nK) stage(cur ^ 1, kc + 1);
        const unsigned char* as = AsB[cur];
        const unsigned char* wsb = WsB[cur];
        const unsigned char* ws2 = Ws2B[DUAL ? cur : 0];
#pragma unroll
        for (int ks = 0; ks < 2; ++ks) {
            short8 af[4], wf[NCB], wf2[2];
#pragma unroll
            for (int rb = 0; rb < 4; ++rb)
                af[rb] = *reinterpret_cast<const short8*>(
                    &as[swz((wr * 64 + rb * 16 + lr) * 128 + ks * 64 + lg * 16)]);
#pragma unroll
            for (int cb = 0; cb < NCB; ++cb) {
                wf[cb] = *reinterpret_cast<const short8*>(
                    &wsb[swz((wc * WCOL + cb * 16 + lr) * 128 + ks * 64 + lg * 16)]);
                if (DUAL && cb < 2)
                    wf2[cb] = *reinterpret_cast<const short8*>(
                        &ws2[swz((wc * 32 + cb * 16 + lr) * 128 + ks * 64 + lg * 16)]);
            }
#pragma unroll
            for (int rb = 0; rb < 4; ++rb)
#pragma unroll
                for (int cb = 0; cb < NCB; ++cb) {
                    acc[rb][cb] = MFMA(af[rb], wf[cb], acc[rb][cb], 0, 0, 0);
                    if (DUAL && cb < 2)
                        acc2[rb][cb] = MFMA(af[rb], wf2[cb], acc2[rb][cb], 0, 0, 0);
                }
        }
        __syncthreads();
    }

    if (MODE == 5) {
        // Dual epilogue: both outputs into parallel LDS buffers, one barrier,
        // interleaved global write passes.
        bf16* eb1 = (bf16*)AsB[0];
        bf16* eb2 = (bf16*)AsB[1];
        // hoist PB (resid) loads so their L2 latency hides under eb1 compute
        float pbv[4][2][4];
#pragma unroll
        for (int rb = 0; rb < 4; ++rb)
#pragma unroll
            for (int r = 0; r < 4; ++r) {
                int ml = wr * 64 + rb * 16 + lg * 4 + r;
#pragma unroll
                for (int cb = 0; cb < 2; ++cb)
                    pbv[rb][cb][r] = resid[(ml & 127) * 576 + n0 + wc * 32 + cb * 16 + lr];
            }
#pragma unroll
        for (int rb = 0; rb < 4; ++rb)
#pragma unroll
            for (int r = 0; r < 4; ++r) {
                int ml = wr * 64 + rb * 16 + lg * 4 + r;
#pragma unroll
                for (int cb = 0; cb < 2; ++cb) {
                    int cl = wc * 32 + cb * 16 + lr;
                    int n = n0 + cl;
                    eb1[ml * 64 + cl] = __float2bfloat16(acc[rb][cb][r] + B1[n]);
                    eb2[ml * 64 + cl] = __float2bfloat16(acc2[rb][cb][r] + pbv[rb][cb][r]);
                }
            }
        __syncthreads();
        bf16* Og  = (bf16*)outp;
        bf16* Og2 = (bf16*)outp2;
#pragma unroll
        for (int it = 0; it < 4; ++it) {
            int idx = it * 256 + tid;
            int row = idx >> 3, g = idx & 7;
            uint4 v1 = *reinterpret_cast<const uint4*>(&eb1[row * 64 + g * 8]);
            uint4 v2 = *reinterpret_cast<const uint4*>(&eb2[row * 64 + g * 8]);
            *reinterpret_cast<uint4*>(Og  + (size_t)(m0 + row) * 576 + n0 + g * 8) = v1;
            *reinterpret_cast<uint4*>(Og2 + (size_t)(m0 + row) * 576 + n0 + g * 8) = v2;
        }
    } else if (MODE == 3) {
        bf16* eb = (bf16*)AsB[0];
#pragma unroll
        for (int rb = 0; rb < 4; ++rb)
#pragma unroll
            for (int r = 0; r < 4; ++r) {
                int ml = wr * 64 + rb * 16 + lg * 4 + r;
#pragma unroll
                for (int cb = 0; cb < 2; ++cb) {
                    int cl = wc * 32 + cb * 16 + lr;
                    int n = n0 + cl;
                    float u = acc[rb][cb][r] + B1[n];
                    float v2 = acc2[rb][cb][r] + B2[n];
                    float t = u * (0.7978845608028654f + 0.0356774081363001f * u * u);
                    float g = u * v2 / (1.0f + __expf(-2.0f * t));
                    eb[ml * 64 + cl] = __float2bfloat16(g);
                }
            }
        __syncthreads();
        bf16* Og = (bf16*)outp;
#pragma unroll
        for (int it = 0; it < 4; ++it) {
            int idx = it * 256 + tid;
            int row = idx >> 3, g = idx & 7;
            uint4 v = *reinterpret_cast<const uint4*>(&eb[row * 64 + g * 8]);
            *reinterpret_cast<uint4*>(Og + (size_t)(m0 + row) * 384 + n0 + g * 8) = v;
        }
    } else {
#pragma unroll
        for (int rb = 0; rb < 4; ++rb) {
#pragma unroll
            for (int r = 0; r < 4; ++r) {
                int m = m0 + wr * 64 + rb * 16 + lg * 4 + r;
                if (MODE == 2) {
                    int win = m >> 7, t = m & 127;
                    int bb = win >> 9, rem = win & 511;
                    int sd = ((rem >> 8) << 1) | (t >> 6);
                    int sh = (((rem >> 4) & 15) << 3) | ((t >> 3) & 7);
                    int sw = ((rem & 15) << 3) | (t & 7);
                    int dq = (sd + 1) & 3;
                    int hq = (sh + 4) & 127;
                    int wq = (sw + 4) & 127;
                    size_t gb = ((((size_t)bb * 4 + dq) * 128 + hq) * 128 + wq) * 192;
                    float* Rr = (float*)outp;
#pragma unroll
                    for (int cb = 0; cb < NCB; ++cb) {
                        int n = n0 + wc * WCOL + cb * 16 + lr;
                        Rr[gb + n] = resid[gb + n] + acc[rb][cb][r] + B1[n];
                    }
                } else {
                    float* Og = (float*)outp;
#pragma unroll
                    for (int cb = 0; cb < NCB; ++cb) {
                        int n = n0 + wc * WCOL + cb * 16 + lr;
                        Og[(size_t)m * 192 + n] =
                            resid[(size_t)m * 192 + n] + acc[rb][cb][r] + B1[n];
                    }
                }
            }
        }
    }
}

// ---------------- MFMA self attention (half-grid; vectorized V-staging) ------
__global__ __launch_bounds__(256) void attn_self(
    const bf16* __restrict__ Qb, const bf16* __restrict__ rpbF,
    const bf16* __restrict__ mskF, bf16* __restrict__ Ob, int b2) {
    __shared__ __align__(16) bf16 VtB[4096];        // V^T [32][128], granule-XOR swizzled
    __shared__ __align__(16) bf16 EpiB[4][1280];    // per-wave [32][40]
    int bid = blockIdx.x;
    int lin = (bid & 7) * 384 + (bid >> 3);         // 3072 blocks
    int widx = lin / 6, h = lin - widx * 6;
    int win = b2 * 512 + widx;                      // global window (O indexing)
    int tid = threadIdx.x, w = tid >> 6, l = tid & 63;
    int lr = l & 15, lg = l >> 4;
    const float qscale = 0.17677669529663689f;
    size_t qbase = (size_t)widx * 128 * 576 + h * 32;   // local to this half's Q

    // V staging: ushort4 (4 bf16) vector loads
    {
        unsigned short* VtU = reinterpret_cast<unsigned short*>(VtB);
#pragma unroll
        for (int it = 0; it < 4; ++it) {
            int idx = it * 256 + tid;       // 1024 tasks = 128 j x 8 d-groups
            int dg = idx & 7, j = idx >> 3;
            int d0 = dg * 4;
            union { ushort4 u; unsigned short s[4]; } cv;
            cv.u = *reinterpret_cast<const ushort4*>(Qb + qbase + (size_t)j * 576 + 384 + d0);
            int jsw = (j & 7) * 2;
            int jhi = j >> 3;
#pragma unroll
            for (int k = 0; k < 4; ++k) {
                int d = d0 + k;
                VtU[(d * 256 + ((jhi ^ (d & 7)) << 4) + jsw) >> 1] = cv.s[k];
            }
        }
    }

    uint4 kf[8], qf[2];
#pragma unroll
    for (int jb = 0; jb < 8; ++jb)
        kf[jb] = *reinterpret_cast<const uint4*>(Qb + qbase + (size_t)(jb * 16 + lr) * 576 + 192 + lg * 8);
    int i0 = w * 32;
#pragma unroll
    for (int ib = 0; ib < 2; ++ib)
        qf[ib] = *reinterpret_cast<const uint4*>(Qb + qbase + (size_t)(i0 + ib * 16 + lr) * 576 + lg * 8);
    f32x4 s[8][2] = {};
#pragma unroll
    for (int jb = 0; jb < 8; ++jb)
#pragma unroll
        for (int ib = 0; ib < 2; ++ib)
            s[jb][ib] = MFMA(u4s8(kf[jb]), u4s8(qf[ib]), s[jb][ib], 0, 0, 0);

    // scale + rpb + mask via fragment-quad layout: one uint2 per table per (jb,ib)
    const bf16* rpF = rpbF + (size_t)h * 16384;
    const bf16* mpF = mskF + (size_t)widx * 16384;
#pragma unroll
    for (int jb = 0; jb < 8; ++jb) {
        int jq0 = jb * 4 + lg;
#pragma unroll
        for (int ib = 0; ib < 2; ++ib) {
            int il = i0 + ib * 16 + lr;
            uint2 rv = *reinterpret_cast<const uint2*>(rpF + (jq0 * 128 + il) * 4);
            uint2 mv = *reinterpret_cast<const uint2*>(mpF + (jq0 * 128 + il) * 4);
            s[jb][ib][0] = fmaf(s[jb][ib][0], qscale, u2f(rv.x & 0xffffu) + u2f(mv.x & 0xffffu));
            s[jb][ib][1] = fmaf(s[jb][ib][1], qscale, u2f(rv.x >> 16) + u2f(mv.x >> 16));
            s[jb][ib][2] = fmaf(s[jb][ib][2], qscale, u2f(rv.y & 0xffffu) + u2f(mv.y & 0xffffu));
            s[jb][ib][3] = fmaf(s[jb][ib][3], qscale, u2f(rv.y >> 16) + u2f(mv.y >> 16));
        }
    }

    float rs[2];
    unsigned w0[2][8], w1[2][8];
#pragma unroll
    for (int ib = 0; ib < 2; ++ib) {
        float mx = -1e30f;
#pragma unroll
        for (int jb = 0; jb < 8; ++jb)
#pragma unroll
            for (int r = 0; r < 4; ++r) mx = fmaxf(mx, s[jb][ib][r]);
        mx = fmaxf(mx, __shfl_xor(mx, 16));
        mx = fmaxf(mx, __shfl_xor(mx, 32));
        float sum = 0.0f;
#pragma unroll
        for (int jb = 0; jb < 8; ++jb)
#pragma unroll
            for (int r = 0; r < 4; ++r) {
                float e = __expf(s[jb][ib][r] - mx);
                s[jb][ib][r] = e;
                sum += e;
            }
        sum += __shfl_xor(sum, 16);
        sum += __shfl_xor(sum, 32);
        rs[ib] = 1.0f / sum;
#pragma unroll
        for (int jb = 0; jb < 8; ++jb) {
            w0[ib][jb] = pkbf(s[jb][ib][0], s[jb][ib][1]);
            w1[ib][jb] = pkbf(s[jb][ib][2], s[jb][ib][3]);
        }
    }
    __syncthreads();

    f32x4 o[2][2] = {};
    int srcA = lr + 16 * (2 * (lg & 1));
    int srcB = srcA + 16;
    bool hi = ((lg >> 1) & 1) != 0;
#pragma unroll
    for (int ks = 0; ks < 4; ++ks) {
        short8 vt[2];
#pragma unroll
        for (int db = 0; db < 2; ++db) {
            int d = db * 16 + lr;
            vt[db] = *reinterpret_cast<const short8*>(
                &VtB[(d * 256 + (((ks * 4 + lg) ^ (d & 7)) << 4)) >> 1]);
        }
#pragma unroll
        for (int ib = 0; ib < 2; ++ib) {
            unsigned xa0 = (unsigned)__shfl((int)w0[ib][2 * ks], srcA, 64);
            unsigned xa1 = (unsigned)__shfl((int)w0[ib][2 * ks + 1], srcA, 64);
            unsigned xb0 = (unsigned)__shfl((int)w1[ib][2 * ks], srcA, 64);
            unsigned xb1 = (unsigned)__shfl((int)w1[ib][2 * ks + 1], srcA, 64);
            unsigned xc0 = (unsigned)__shfl((int)w0[ib][2 * ks], srcB, 64);
            unsigned xc1 = (unsigned)__shfl((int)w0[ib][2 * ks + 1], srcB, 64);
            unsigned xd0 = (unsigned)__shfl((int)w1[ib][2 * ks], srcB, 64);
            unsigned xd1 = (unsigned)__shfl((int)w1[ib][2 * ks + 1], srcB, 64);
            uint4 bfv;
            bfv.x = hi ? xa1 : xa0;
            bfv.y = hi ? xb1 : xb0;
            bfv.z = hi ? xc1 : xc0;
            bfv.w = hi ? xd1 : xd0;
            short8 pb = u4s8(bfv);
#pragma unroll
            for (int db = 0; db < 2; ++db) o[db][ib] = MFMA(vt[db], pb, o[db][ib], 0, 0, 0);
        }
    }

    bf16* eb = &EpiB[w][0];
#pragma unroll
    for (int db = 0; db < 2; ++db)
#pragma unroll
        for (int ib = 0; ib < 2; ++ib)
#pragma unroll
            for (int r = 0; r < 4; ++r) {
                int d = db * 16 + lg * 4 + r;
                int il = ib * 16 + lr;
                eb[il * 40 + d] = __float2bfloat16(o[db][ib][r] * rs[ib]);
            }
    int il2 = l >> 1, hf = l & 1;
    uint4 oa = *reinterpret_cast<const uint4*>(&eb[il2 * 40 + hf * 16]);
    uint4 ob2 = *reinterpret_cast<const uint4*>(&eb[il2 * 40 + hf * 16 + 8]);
    size_t gbase = ((size_t)win * 128 + i0 + il2) * 384 + 192 + h * 32 + hf * 16;
    *reinterpret_cast<uint4*>(Ob + gbase) = oa;
    *reinterpret_cast<uint4*>(Ob + gbase + 8) = ob2;
}

// ---------------- MFMA mutual attention (half-grid; vectorized V-staging) ----
__global__ __launch_bounds__(256) void attn_mut(
    const bf16* __restrict__ Qb, const bf16* __restrict__ mskF, bf16* __restrict__ Ob,
    int b2) {
    __shared__ __align__(16) bf16 VtB[4096];
    __shared__ __align__(16) bf16 EpiB[4][1280];
    int bid = blockIdx.x;
    int lin = (bid & 7) * 384 + (bid >> 3);         // 3072 blocks
    int widx = lin / 6, h = lin - widx * 6;
    int win = b2 * 512 + widx;
    int tid = threadIdx.x, w = tid >> 6, l = tid & 63;
    int lr = l & 15, lg = l >> 4;
    const float qscale = 0.17677669529663689f;
    size_t qbase = (size_t)widx * 128 * 576 + h * 32;   // local to this half's Q2

    {
        unsigned short* VtU = reinterpret_cast<unsigned short*>(VtB);
#pragma unroll
        for (int it = 0; it < 4; ++it) {
            int idx = it * 256 + tid;
            int dg = idx & 7, j = idx >> 3;
            int d0 = dg * 4;
            union { ushort4 u; unsigned short s[4]; } cv;
            cv.u = *reinterpret_cast<const ushort4*>(Qb + qbase + (size_t)j * 576 + 384 + d0);
            int jsw = (j & 7) * 2;
            int jhi = j >> 3;
#pragma unroll
            for (int k = 0; k < 4; ++k) {
                int d = d0 + k;
                VtU[(d * 256 + ((jhi ^ (d & 7)) << 4) + jsw) >> 1] = cv.s[k];
            }
        }
    }

    int i0 = w * 32;
    int qoff = (w < 2) ? 64 : -64;
    int koff = (w < 2) ? 0 : 64;
    uint4 kf[4], qf[2];
#pragma unroll
    for (int jb = 0; jb < 4; ++jb)
        kf[jb] = *reinterpret_cast<const uint4*>(
            Qb + qbase + (size_t)(koff + jb * 16 + lr) * 576 + 192 + lg * 8);
#pragma unroll
    for (int ib = 0; ib < 2; ++ib)
        qf[ib] = *reinterpret_cast<const uint4*>(
            Qb + qbase + (size_t)(i0 + ib * 16 + lr + qoff) * 576 + lg * 8);
    f32x4 s[4][2] = {};
#pragma unroll
    for (int jb = 0; jb < 4; ++jb)
#pragma unroll
        for (int ib = 0; ib < 2; ++ib)
            s[jb][ib] = MFMA(u4s8(kf[jb]), u4s8(qf[ib]), s[jb][ib], 0, 0, 0);

    const bf16* mpF = mskF + (size_t)widx * 16384;
    int ibase = (i0 & 63);
#pragma unroll
    for (int jb = 0; jb < 4; ++jb) {
        int jq0 = jb * 4 + lg;
#pragma unroll
        for (int ib = 0; ib < 2; ++ib) {
            int il = ibase + ib * 16 + lr;
            uint2 mv = *reinterpret_cast<const uint2*>(mpF + (jq0 * 128 + il) * 4);
            s[jb][ib][0] = fmaf(s[jb][ib][0], qscale, u2f(mv.x & 0xffffu));
            s[jb][ib][1] = fmaf(s[jb][ib][1], qscale, u2f(mv.x >> 16));
            s[jb][ib][2] = fmaf(s[jb][ib][2], qscale, u2f(mv.y & 0xffffu));
            s[jb][ib][3] = fmaf(s[jb][ib][3], qscale, u2f(mv.y >> 16));
        }
    }

    float rs[2];
    unsigned w0[2][4], w1[2][4];
#pragma unroll
    for (int ib = 0; ib < 2; ++ib) {
        float mx = -1e30f;
#pragma unroll
        for (int jb = 0; jb < 4; ++jb)
#pragma unroll
            for (int r = 0; r < 4; ++r) mx = fmaxf(mx, s[jb][ib][r]);
        mx = fmaxf(mx, __shfl_xor(mx, 16));
        mx = fmaxf(mx, __shfl_xor(mx, 32));
        float sum = 0.0f;
#pragma unroll
        for (int jb = 0; jb < 4; ++jb)
#pragma unroll
            for (int r = 0; r < 4; ++r) {
                float e = __expf(s[jb][ib][r] - mx);
                s[jb][ib][r] = e;
                sum += e;
            }
        sum += __shfl_xor(sum, 16);
        sum += __shfl_xor(sum, 32);
        rs[ib] = 1.0f / sum;
#pragma unroll
        for (int jb = 0; jb < 4; ++jb) {
            w0[ib][jb] = pkbf(s[jb][ib][0], s[jb][ib][1]);
            w1[ib][jb] = pkbf(s[jb][ib][2], s[jb][ib][3]);
        }
    }
    __syncthreads();

    f32x4 o[2][2] = {};
    int srcA = lr + 16 * (2 * (lg & 1));
    int srcB = srcA + 16;
    bool hi = ((lg >> 1) & 1) != 0;
    int gb0 = koff >> 3;
#pragma unroll
    for (int ks = 0; ks < 2; ++ks) {
        short8 vt[2];
#pragma unroll
        for (int db = 0; db < 2; ++db) {
            int d = db * 16 + lr;
            vt[db] = *reinterpret_cast<const short8*>(
                &VtB[(d * 256 + (((gb0 + ks * 4 + lg) ^ (d & 7)) << 4)) >> 1]);
        }
#pragma unroll
        for (int ib = 0; ib < 2; ++ib) {
            unsigned xa0 = (unsigned)__shfl((int)w0[ib][2 * ks], srcA, 64);
            unsigned xa1 = (unsigned)__shfl((int)w0[ib][2 * ks + 1], srcA, 64);
            unsigned xb0 = (unsigned)__shfl((int)w1[ib][2 * ks], srcA, 64);
            unsigned xb1 = (unsigned)__shfl((int)w1[ib][2 * ks + 1], srcA, 64);
            unsigned xc0 = (unsigned)__shfl((int)w0[ib][2 * ks], srcB, 64);
            unsigned xc1 = (unsigned)__shfl((int)w0[ib][2 * ks + 1], srcB, 64);
            unsigned xd0 = (unsigned)__shfl((int)w1[ib][2 * ks], srcB, 64);
            unsigned xd1 = (unsigned)__shfl((int)w1[ib][2 * ks + 1], srcB, 64);
            uint4 bfv;
            bfv.x = hi ? xa1 : xa0;
            bfv.y = hi ? xb1 : xb0;
            bfv.z = hi ? xc1 : xc0;
            bfv.w = hi ? xd1 : xd0;
            short8 pb = u4s8(bfv);
#pragma unroll
            for (int db = 0; db < 2; ++db) o[db][ib] = MFMA(vt[db], pb, o[db][ib], 0, 0, 0);
        }
    }

    bf16* eb = &EpiB[w][0];
#pragma unroll
    for (int db = 0; db < 2; ++db)
#pragma unroll
        for (int ib = 0; ib < 2; ++ib)
#pragma unroll
            for (int r = 0; r < 4; ++r) {
                int d = db * 16 + lg * 4 + r;
                int il = ib * 16 + lr;
                eb[il * 40 + d] = __float2bfloat16(o[db][ib][r] * rs[ib]);
            }
    int il2 = l >> 1, hf = l & 1;
    uint4 oa = *reinterpret_cast<const uint4*>(&eb[il2 * 40 + hf * 16]);
    uint4 ob2 = *reinterpret_cast<const uint4*>(&eb[il2 * 40 + hf * 16 + 8]);
    size_t gbase = ((size_t)win * 128 + i0 + il2) * 384 + h * 32 + hf * 16;
    *reinterpret_cast<uint4*>(Ob + gbase) = oa;
    *reinterpret_cast<uint4*>(Ob + gbase + 8) = ob2;
}

// ---------------------------------------------------------------------------
extern "C" void kernel_launch(void* const* d_in, const int* in_sizes, int n_in,
                              void* d_out, int out_size, void* d_ws, size_t ws_size,
                              hipStream_t stream) {
    const float* x    = (const float*)d_in[0];
    const float* mask = (const float*)d_in[1];
    const float* n1w  = (const float*)d_in[2];
    const float* n1b  = (const float*)d_in[3];
    const float* wqs  = (const float*)d_in[4];
    const float* bqs  = (const float*)d_in[5];
    const float* wqm  = (const float*)d_in[6];
    const float* bqm  = (const float*)d_in[7];
    const float* rpbt = (const float*)d_in[8];
    const float* wproj= (const float*)d_in[9];
    const float* bproj= (const float*)d_in[10];
    const float* n2w  = (const float*)d_in[11];
    const float* n2b  = (const float*)d_in[12];
    const float* w11  = (const float*)d_in[13];
    const float* b11  = (const float*)d_in[14];
    const float* w12  = (const float*)d_in[15];
    const float* b12  = (const float*)d_in[16];
    const float* w2   = (const float*)d_in[17];
    const float* b2   = (const float*)d_in[18];

    char* ws = (char*)d_ws;
    bf16*  A    = (bf16*)(ws + A_OFF);
    bf16*  Q    = (bf16*)(ws + Q_OFF);
    bf16*  O    = (bf16*)(ws + O_OFF);
    float* pos  = (float*)(ws + POS_OFF);
    float* PB   = (float*)(ws + PB_OFF);
    bf16*  rpbF = (bf16*)(ws + RPBF_OFF);
    bf16*  mskF = (bf16*)(ws + MSKF_OFF);
    bf16*  WB   = (bf16*)(ws + WB_OFF);
    bf16*  Hb = A;               // reuse: A dead after dual qkv
    bf16*  G  = Q;               // reuse: Q dead after attention
    float* R  = (float*)d_out;
    float* out = (float*)d_out;
    // Q2 scratch for mutual QKV: d_out region (100.7 MB) is dead until proj
    // overwrites all of R. Per-half mutual QKV needs 65536*576*2B = 75.5 MB.
    bf16*  Q2 = (bf16*)d_out;

    cvtw_kernel<<<(WTOT + 255) / 256, 256, 0, stream>>>(wqs, wqm, wproj, w11, w12, w2, WB);
    pos_kernel<<<96, 256, 0, stream>>>(pos);
    pbias_kernel<<<288, 256, 0, stream>>>(pos, WB + WQM_E, bqm, PB);
    rpbF_kernel<<<384, 256, 0, stream>>>(rpbt, rpbF);
    mskF_kernel<<<8192, 256, 0, stream>>>(mask, mskF);
    ln_kernel<1><<<32768, 256, 0, stream>>>(x, n1w, n1b, A);

    // fused self+mutual qkv, token-halved so Q2 fits in the d_out scratch
    for (int hf = 0; hf < 2; ++hf) {
        const bf16* Ah = A + (size_t)hf * 65536 * 192;
        bf16* Qh = Q + (size_t)hf * 65536 * 576;
        mgemm<5, 0><<<9 * 512, 256, 0, stream>>>(Ah, 192, 9, WB + WQS_E, bqs, WB + WQM_E,
                                                 nullptr, PB, Qh, Q2);
        attn_self<<<3072, 256, 0, stream>>>(Qh, rpbF, mskF, O, hf);
        attn_mut<<<3072, 256, 0, stream>>>(Q2, mskF, O, hf);
    }

    // proj + window-reverse + roll + residual (BN=192: one block per M row-tile)
    mgemm<2, 0><<<1024, 256, 0, stream>>>(O, 384, 1, WB + WPR_E, bproj, nullptr, nullptr,
                                          x, R, nullptr);
    ln_kernel<0><<<32768, 256, 0, stream>>>(R, n2w, n2b, Hb);
    // fc11 + fc12 + gelu gate
    mgemm<3, 0><<<6 * 1024, 256, 0, stream>>>(Hb, 192, 6, WB + W11_E, b11, WB + W12_E, b12,
                                              nullptr, G, nullptr);
    // fc2 + final residual (BN=192)
    mgemm<4, 0><<<1024, 256, 0, stream>>>(G, 384, 1, WB + W2_E, b2, nullptr, nullptr,
                                          R, out, nullptr);
}

// Round 11
// 565.364 us; speedup vs baseline: 1.0156x; 1.0156x over previous
//
#include <hip/hip_runtime.h>
#include <hip/hip_bf16.h>

typedef __hip_bfloat16 bf16;
typedef __attribute__((ext_vector_type(8))) short short8;
typedef __attribute__((ext_vector_type(4))) float f32x4;

#define NTOKENS 131072   // 2*4*128*128
#define MFMA __builtin_amdgcn_mfma_f32_16x16x32_bf16

// ---- workspace layout (bytes) ----
static constexpr size_t A_OFF    = 0;                                  // xw bf16 [131072][192]
static constexpr size_t Q_OFF    = A_OFF   + (size_t)NTOKENS*192*2;    // qkv bf16 [131072][576]
static constexpr size_t O_OFF    = Q_OFF   + (size_t)NTOKENS*576*2;    // x_out bf16 [131072][384]
static constexpr size_t POS_OFF  = O_OFF   + (size_t)NTOKENS*384*2;    // pos f32 [128][192]
static constexpr size_t PB_OFF   = POS_OFF + (size_t)128*192*4;        // pos@Wm^T+b f32 [128][576]
static constexpr size_t RPBF_OFF = PB_OFF  + (size_t)128*576*4;        // rpbF bf16 [6][32][128][4]
static constexpr size_t MSKF_OFF = RPBF_OFF+ (size_t)6*128*128*2;      // mskF bf16 [512][32][128][4]
static constexpr size_t WB_OFF   = MSKF_OFF+ (size_t)512*128*128*2;    // bf16 weights
static constexpr size_t WQS_E = 0, WQM_E = 110592, WPR_E = 221184,
                        W11_E = 294912, W12_E = 368640, W2_E = 442368, WTOT = 516096;

__device__ __forceinline__ float u2f(unsigned int ubits) {
    union { unsigned int i; float f; } c; c.i = ubits << 16; return c.f;
}
__device__ __forceinline__ unsigned pkbf(float a, float b) {
    unsigned ua = (unsigned)__bfloat16_as_ushort(__float2bfloat16(a));
    unsigned ub = (unsigned)__bfloat16_as_ushort(__float2bfloat16(b));
    return ua | (ub << 16);
}
__device__ __forceinline__ unsigned swz(unsigned b) { return b ^ (((b >> 9) & 1) << 5); }
__device__ __forceinline__ short8 u4s8(uint4 v) { union { uint4 u; short8 s; } c; c.u = v; return c.s; }

// async 16B global->LDS (linear dest; callers pre-permute the SOURCE granule)
__device__ __forceinline__ void gl16(const bf16* g, void* l) {
    __builtin_amdgcn_global_load_lds(
        (const __attribute__((address_space(1))) void*)g,
        (__attribute__((address_space(3))) void*)l, 16, 0, 0);
}

// ---------------- weight fp32 -> bf16 ----------------------------------------
__global__ __launch_bounds__(256) void cvtw_kernel(
    const float* __restrict__ a, const float* __restrict__ b, const float* __restrict__ c,
    const float* __restrict__ d, const float* __restrict__ e, const float* __restrict__ f,
    bf16* __restrict__ out) {
    int i = blockIdx.x * 256 + threadIdx.x;
    const float* src; int off;
    if      (i < (int)WQM_E) { src = a; off = (int)WQS_E; }
    else if (i < (int)WPR_E) { src = b; off = (int)WQM_E; }
    else if (i < (int)W11_E) { src = c; off = (int)WPR_E; }
    else if (i < (int)W12_E) { src = d; off = (int)W11_E; }
    else if (i < (int)W2_E)  { src = e; off = (int)W12_E; }
    else if (i < (int)WTOT)  { src = f; off = (int)W2_E; }
    else return;
    out[i] = __float2bfloat16(src[i - off]);
}

// ---------------- pos table (f32) --------------------------------------------
__global__ __launch_bounds__(256) void pos_kernel(float* __restrict__ pos) {
    int idx = blockIdx.x * 256 + threadIdx.x;
    if (idx >= 128 * 192) return;
    int t = idx / 192, c = idx - t * 192;
    int s = t & 63;
    int hh = s >> 3, ww = s & 7;
    const float twopi = 6.2831853071795864f;
    float coord = (c < 96) ? (float)(hh + 1) : (float)(ww + 1);
    coord = coord / (8.0f + 1e-6f) * twopi;
    int f = (c < 96) ? c : c - 96;
    float dimt = powf(10000.0f, (float)(2 * (f >> 1)) / 96.0f);
    float v = coord / dimt;
    pos[idx] = (f & 1) ? cosf(v) : sinf(v);
}

// ---------------- PB[t][n] = pos[t]·Wm[n] + bqm[n]  (f32) --------------------
__global__ __launch_bounds__(256) void pbias_kernel(const float* __restrict__ pos,
                                                    const bf16* __restrict__ Wm,
                                                    const float* __restrict__ bqm,
                                                    float* __restrict__ PB) {
    int idx = blockIdx.x * 256 + threadIdx.x;
    if (idx >= 128 * 576) return;
    int t = idx / 576, n = idx - t * 576;
    const float* pp = pos + t * 192;
    const bf16* wp = Wm + (size_t)n * 192;
    float acc = bqm[n];
    for (int k = 0; k < 192; ++k) acc += pp[k] * __bfloat162float(wp[k]);
    PB[idx] = acc;
}

// ---- rpbF[h][j>>2][i][j&3] = tbl[relidx(i,j)][h]  (fragment-quad layout) ----
__global__ __launch_bounds__(256) void rpbF_kernel(const float* __restrict__ tbl,
                                                   bf16* __restrict__ rpbF) {
    int idx = blockIdx.x * 256 + threadIdx.x;
    if (idx >= 6 * 32 * 128 * 4) return;
    int jr = idx & 3;
    int i = (idx >> 2) & 127;
    int jq = (idx >> 9) & 31;
    int h = idx >> 14;
    int j = jq * 4 + jr;                       // i = query row, j = key col
    int di = i >> 6, hi = (i >> 3) & 7, wi = i & 7;
    int dj = j >> 6, hj = (j >> 3) & 7, wj = j & 7;
    int t = (di - dj + 1) * 225 + (hi - hj + 7) * 15 + (wi - wj + 7);
    rpbF[idx] = __float2bfloat16(tbl[t * 6 + h]);
}

// ---- mskF[w][j>>2][i][j&3] = bf16(mask[w][i][j]); float4-coalesced reads ----
__global__ __launch_bounds__(256) void mskF_kernel(const float* __restrict__ mask,
                                                   bf16* __restrict__ mskF) {
    int idx = blockIdx.x * 256 + threadIdx.x;   // 512*128*32
    int widx = idx >> 12;
    int rem = idx & 4095;
    int i = rem >> 5, jq = rem & 31;
    float4 v = *reinterpret_cast<const float4*>(mask + ((size_t)widx << 14) + i * 128 + jq * 4);
    uint2 o;
    o.x = pkbf(v.x, v.y);
    o.y = pkbf(v.z, v.w);
    *reinterpret_cast<uint2*>(mskF + ((size_t)widx << 14) + (jq * 128 + i) * 4) = o;
}

// ---------------- LayerNorm (PART=1: + roll + window partition) --------------
template <int PART>
__global__ __launch_bounds__(256) void ln_kernel(const float* __restrict__ xin,
                                                 const float* __restrict__ w,
                                                 const float* __restrict__ b,
                                                 bf16* __restrict__ out) {
    int tok = blockIdx.x * 4 + (threadIdx.x >> 6);
    int lane = threadIdx.x & 63;
    const float* xp = xin + (size_t)tok * 192;
    float x0 = xp[lane], x1 = xp[lane + 64], x2 = xp[lane + 128];
    float s = x0 + x1 + x2;
    float ss = x0 * x0 + x1 * x1 + x2 * x2;
    for (int off = 32; off; off >>= 1) {
        s += __shfl_xor(s, off);
        ss += __shfl_xor(ss, off);
    }
    float mean = s * (1.0f / 192.0f);
    float var = ss * (1.0f / 192.0f) - mean * mean;
    float rstd = rsqrtf(var + 1e-5f);
    size_t obase;
    if (PART) {
        int bb = tok >> 16;
        int rem = tok & 65535;
        int d = rem >> 14;
        int hw = rem & 16383;
        int hh = hw >> 7, w2 = hw & 127;
        int sd = (d + 3) & 3;
        int sh = (hh + 124) & 127;
        int sw = (w2 + 124) & 127;
        int win = ((bb * 2 + (sd >> 1)) * 16 + (sh >> 3)) * 16 + (sw >> 3);
        int t = ((sd & 1) << 6) | ((sh & 7) << 3) | (sw & 7);
        obase = ((size_t)win * 128 + t) * 192;
    } else {
        obase = (size_t)tok * 192;
    }
    out[obase + lane]       = __float2bfloat16((x0 - mean) * rstd * w[lane] + b[lane]);
    out[obase + lane + 64]  = __float2bfloat16((x1 - mean) * rstd * w[lane + 64] + b[lane + 64]);
    out[obase + lane + 128] = __float2bfloat16((x2 - mean) * rstd * w[lane + 128] + b[lane + 128]);
}

// ---------------- MFMA GEMM (round-0 double-buffered structure) --------------
// MODE 2: proj + window-reverse + roll + residual (f32 out)
// MODE 3: fc11+fc12 dual W + gelu-gate (bf16 out stride 384)
// MODE 4: fc2 + residual (f32 out)
// MODE 5: dual W, two bf16 outs stride 576 (fused self+mutual qkv);
//         out1 = acc + B1[n], out2 = acc2 + resid[(ml&127)*576+n]  (PB table)
//         Epilogue: BOTH outputs staged in parallel LDS buffers, ONE barrier,
//         interleaved write passes.
template <int MODE, int BIAS>
__global__ __launch_bounds__(256) void mgemm(
    const bf16* __restrict__ Ab, int K, int nb,
    const bf16* __restrict__ W1, const float* __restrict__ B1,
    const bf16* __restrict__ W2, const float* __restrict__ B2,
    const float* __restrict__ resid,
    void* __restrict__ outp, void* __restrict__ outp2) {
    constexpr bool DUAL = (MODE == 3 || MODE == 5);
    __shared__ __align__(16) unsigned char AsB[2][16384];
    __shared__ __align__(16) unsigned char WsB[2][8192];
    __shared__ __align__(16) unsigned char Ws2B[DUAL ? 2 : 1][DUAL ? 8192 : 16];

    int total = gridDim.x;
    int bid = blockIdx.x;
    int lin = (bid & 7) * (total >> 3) + (bid >> 3);
    int mb = lin / nb, nbk = lin - mb * nb;
    int m0 = mb << 7, n0 = nbk << 6;
    int tid = threadIdx.x;
    int w = tid >> 6, l = tid & 63;
    int wr = w >> 1, wc = w & 1;
    int lr = l & 15, lg = l >> 4;

    f32x4 acc[4][2] = {};
    f32x4 acc2[4][2] = {};

    auto stage = [&](int buf, int kc) {
        int k0 = kc << 6;
#pragma unroll
        for (int it = 0; it < 4; ++it) {
            int idx = it * 256 + tid;
            int row = idx >> 3, gs = idx & 7;
            int gsrc = gs ^ (((row >> 2) & 1) << 1);
            gl16(Ab + (size_t)(m0 + row) * K + k0 + gsrc * 8, &AsB[buf][idx * 16]);
        }
#pragma unroll
        for (int it = 0; it < 2; ++it) {
            int idx = it * 256 + tid;
            int row = idx >> 3, gs = idx & 7;
            int gsrc = gs ^ (((row >> 2) & 1) << 1);
            gl16(W1 + (size_t)(n0 + row) * K + k0 + gsrc * 8, &WsB[buf][idx * 16]);
            if (DUAL)
                gl16(W2 + (size_t)(n0 + row) * K + k0 + gsrc * 8, &Ws2B[buf][idx * 16]);
        }
    };

    int nK = K >> 6;
    stage(0, 0);
    __syncthreads();
    for (int kc = 0; kc < nK; ++kc) {
        int cur = kc & 1;
        if (kc + 1 < nK) stage(cur ^ 1, kc + 1);
        const unsigned char* as = AsB[cur];
        const unsigned char* wsb = WsB[cur];
        const unsigned char* ws2 = Ws2B[DUAL ? cur : 0];
#pragma unroll
        for (int ks = 0; ks < 2; ++ks) {
            short8 af[4], wf[2], wf2[2];
#pragma unroll
            for (int rb = 0; rb < 4; ++rb)
                af[rb] = *reinterpret_cast<const short8*>(
                    &as[swz((wr * 64 + rb * 16 + lr) * 128 + ks * 64 + lg * 16)]);
#pragma unroll
            for (int cb = 0; cb < 2; ++cb) {
                wf[cb] = *reinterpret_cast<const short8*>(
                    &wsb[swz((wc * 32 + cb * 16 + lr) * 128 + ks * 64 + lg * 16)]);
                if (DUAL)
                    wf2[cb] = *reinterpret_cast<const short8*>(
                        &ws2[swz((wc * 32 + cb * 16 + lr) * 128 + ks * 64 + lg * 16)]);
            }
#pragma unroll
            for (int rb = 0; rb < 4; ++rb)
#pragma unroll
                for (int cb = 0; cb < 2; ++cb) {
                    acc[rb][cb] = MFMA(af[rb], wf[cb], acc[rb][cb], 0, 0, 0);
                    if (DUAL) acc2[rb][cb] = MFMA(af[rb], wf2[cb], acc2[rb][cb], 0, 0, 0);
                }
        }
        __syncthreads();
    }

    if (MODE == 5) {
        // Dual epilogue: both outputs into parallel LDS buffers, one barrier,
        // interleaved global write passes.
        bf16* eb1 = (bf16*)AsB[0];
        bf16* eb2 = (bf16*)AsB[1];
        // hoist PB (resid) loads so their L2 latency hides under eb1 compute
        float pbv[4][2][4];
#pragma unroll
        for (int rb = 0; rb < 4; ++rb)
#pragma unroll
            for (int r = 0; r < 4; ++r) {
                int ml = wr * 64 + rb * 16 + lg * 4 + r;
#pragma unroll
                for (int cb = 0; cb < 2; ++cb)
                    pbv[rb][cb][r] = resid[(ml & 127) * 576 + n0 + wc * 32 + cb * 16 + lr];
            }
#pragma unroll
        for (int rb = 0; rb < 4; ++rb)
#pragma unroll
            for (int r = 0; r < 4; ++r) {
                int ml = wr * 64 + rb * 16 + lg * 4 + r;
#pragma unroll
                for (int cb = 0; cb < 2; ++cb) {
                    int cl = wc * 32 + cb * 16 + lr;
                    int n = n0 + cl;
                    eb1[ml * 64 + cl] = __float2bfloat16(acc[rb][cb][r] + B1[n]);
                    eb2[ml * 64 + cl] = __float2bfloat16(acc2[rb][cb][r] + pbv[rb][cb][r]);
                }
            }
        __syncthreads();
        bf16* Og  = (bf16*)outp;
        bf16* Og2 = (bf16*)outp2;
#pragma unroll
        for (int it = 0; it < 4; ++it) {
            int idx = it * 256 + tid;
            int row = idx >> 3, g = idx & 7;
            uint4 v1 = *reinterpret_cast<const uint4*>(&eb1[row * 64 + g * 8]);
            uint4 v2 = *reinterpret_cast<const uint4*>(&eb2[row * 64 + g * 8]);
            *reinterpret_cast<uint4*>(Og  + (size_t)(m0 + row) * 576 + n0 + g * 8) = v1;
            *reinterpret_cast<uint4*>(Og2 + (size_t)(m0 + row) * 576 + n0 + g * 8) = v2;
        }
    } else if (MODE == 3) {
        bf16* eb = (bf16*)AsB[0];
#pragma unroll
        for (int rb = 0; rb < 4; ++rb)
#pragma unroll
            for (int r = 0; r < 4; ++r) {
                int ml = wr * 64 + rb * 16 + lg * 4 + r;
#pragma unroll
                for (int cb = 0; cb < 2; ++cb) {
                    int cl = wc * 32 + cb * 16 + lr;
                    int n = n0 + cl;
                    float u = acc[rb][cb][r] + B1[n];
                    float v2 = acc2[rb][cb][r] + B2[n];
                    float t = u * (0.7978845608028654f + 0.0356774081363001f * u * u);
                    float g = u * v2 / (1.0f + __expf(-2.0f * t));
                    eb[ml * 64 + cl] = __float2bfloat16(g);
                }
            }
        __syncthreads();
        bf16* Og = (bf16*)outp;
#pragma unroll
        for (int it = 0; it < 4; ++it) {
            int idx = it * 256 + tid;
            int row = idx >> 3, g = idx & 7;
            uint4 v = *reinterpret_cast<const uint4*>(&eb[row * 64 + g * 8]);
            *reinterpret_cast<uint4*>(Og + (size_t)(m0 + row) * 384 + n0 + g * 8) = v;
        }
    } else {
#pragma unroll
        for (int rb = 0; rb < 4; ++rb) {
#pragma unroll
            for (int r = 0; r < 4; ++r) {
                int m = m0 + wr * 64 + rb * 16 + lg * 4 + r;
                if (MODE == 2) {
                    int win = m >> 7, t = m & 127;
                    int bb = win >> 9, rem = win & 511;
                    int sd = ((rem >> 8) << 1) | (t >> 6);
                    int sh = (((rem >> 4) & 15) << 3) | ((t >> 3) & 7);
                    int sw = ((rem & 15) << 3) | (t & 7);
                    int dq = (sd + 1) & 3;
                    int hq = (sh + 4) & 127;
                    int wq = (sw + 4) & 127;
                    size_t gb = ((((size_t)bb * 4 + dq) * 128 + hq) * 128 + wq) * 192;
                    float* Rr = (float*)outp;
#pragma unroll
                    for (int cb = 0; cb < 2; ++cb) {
                        int n = n0 + wc * 32 + cb * 16 + lr;
                        Rr[gb + n] = resid[gb + n] + acc[rb][cb][r] + B1[n];
                    }
                } else {
                    float* Og = (float*)outp;
#pragma unroll
                    for (int cb = 0; cb < 2; ++cb) {
                        int n = n0 + wc * 32 + cb * 16 + lr;
                        Og[(size_t)m * 192 + n] =
                            resid[(size_t)m * 192 + n] + acc[rb][cb][r] + B1[n];
                    }
                }
            }
        }
    }
}

// ---------------- MFMA self attention (half-grid: b2 passed in) --------------
__global__ __launch_bounds__(256) void attn_self(
    const bf16* __restrict__ Qb, const bf16* __restrict__ rpbF,
    const bf16* __restrict__ mskF, bf16* __restrict__ Ob, int b2) {
    __shared__ __align__(16) bf16 VtB[4096];        // V^T [32][128], granule-XOR swizzled
    __shared__ __align__(16) bf16 EpiB[4][1280];    // per-wave [32][40]
    int bid = blockIdx.x;
    int lin = (bid & 7) * 384 + (bid >> 3);         // 3072 blocks
    int widx = lin / 6, h = lin - widx * 6;
    int win = b2 * 512 + widx;                      // global window (O indexing)
    int tid = threadIdx.x, w = tid >> 6, l = tid & 63;
    int lr = l & 15, lg = l >> 4;
    const float qscale = 0.17677669529663689f;
    size_t qbase = (size_t)widx * 128 * 576 + h * 32;   // local to this half's Q

#pragma unroll
    for (int it = 0; it < 16; ++it) {
        int idx = it * 256 + tid;
        int d = idx & 31, j = idx >> 5;
        bf16 v = Qb[qbase + (size_t)j * 576 + 384 + d];
        VtB[(d * 256 + (((j >> 3) ^ (d & 7)) << 4) + (j & 7) * 2) >> 1] = v;
    }

    uint4 kf[8], qf[2];
#pragma unroll
    for (int jb = 0; jb < 8; ++jb)
        kf[jb] = *reinterpret_cast<const uint4*>(Qb + qbase + (size_t)(jb * 16 + lr) * 576 + 192 + lg * 8);
    int i0 = w * 32;
#pragma unroll
    for (int ib = 0; ib < 2; ++ib)
        qf[ib] = *reinterpret_cast<const uint4*>(Qb + qbase + (size_t)(i0 + ib * 16 + lr) * 576 + lg * 8);
    f32x4 s[8][2] = {};
#pragma unroll
    for (int jb = 0; jb < 8; ++jb)
#pragma unroll
        for (int ib = 0; ib < 2; ++ib)
            s[jb][ib] = MFMA(u4s8(kf[jb]), u4s8(qf[ib]), s[jb][ib], 0, 0, 0);

    // scale + rpb + mask via fragment-quad layout: one uint2 per table per (jb,ib)
    const bf16* rpF = rpbF + (size_t)h * 16384;
    const bf16* mpF = mskF + (size_t)widx * 16384;
#pragma unroll
    for (int jb = 0; jb < 8; ++jb) {
        int jq0 = jb * 4 + lg;
#pragma unroll
        for (int ib = 0; ib < 2; ++ib) {
            int il = i0 + ib * 16 + lr;
            uint2 rv = *reinterpret_cast<const uint2*>(rpF + (jq0 * 128 + il) * 4);
            uint2 mv = *reinterpret_cast<const uint2*>(mpF + (jq0 * 128 + il) * 4);
            s[jb][ib][0] = fmaf(s[jb][ib][0], qscale, u2f(rv.x & 0xffffu) + u2f(mv.x & 0xffffu));
            s[jb][ib][1] = fmaf(s[jb][ib][1], qscale, u2f(rv.x >> 16) + u2f(mv.x >> 16));
            s[jb][ib][2] = fmaf(s[jb][ib][2], qscale, u2f(rv.y & 0xffffu) + u2f(mv.y & 0xffffu));
            s[jb][ib][3] = fmaf(s[jb][ib][3], qscale, u2f(rv.y >> 16) + u2f(mv.y >> 16));
        }
    }

    float rs[2];
    unsigned w0[2][8], w1[2][8];
#pragma unroll
    for (int ib = 0; ib < 2; ++ib) {
        float mx = -1e30f;
#pragma unroll
        for (int jb = 0; jb < 8; ++jb)
#pragma unroll
            for (int r = 0; r < 4; ++r) mx = fmaxf(mx, s[jb][ib][r]);
        mx = fmaxf(mx, __shfl_xor(mx, 16));
        mx = fmaxf(mx, __shfl_xor(mx, 32));
        float sum = 0.0f;
#pragma unroll
        for (int jb = 0; jb < 8; ++jb)
#pragma unroll
            for (int r = 0; r < 4; ++r) {
                float e = __expf(s[jb][ib][r] - mx);
                s[jb][ib][r] = e;
                sum += e;
            }
        sum += __shfl_xor(sum, 16);
        sum += __shfl_xor(sum, 32);
        rs[ib] = 1.0f / sum;
#pragma unroll
        for (int jb = 0; jb < 8; ++jb) {
            w0[ib][jb] = pkbf(s[jb][ib][0], s[jb][ib][1]);
            w1[ib][jb] = pkbf(s[jb][ib][2], s[jb][ib][3]);
        }
    }
    __syncthreads();

    f32x4 o[2][2] = {};
    int srcA = lr + 16 * (2 * (lg & 1));
    int srcB = srcA + 16;
    bool hi = ((lg >> 1) & 1) != 0;
#pragma unroll
    for (int ks = 0; ks < 4; ++ks) {
        short8 vt[2];
#pragma unroll
        for (int db = 0; db < 2; ++db) {
            int d = db * 16 + lr;
            vt[db] = *reinterpret_cast<const short8*>(
                &VtB[(d * 256 + (((ks * 4 + lg) ^ (d & 7)) << 4)) >> 1]);
        }
#pragma unroll
        for (int ib = 0; ib < 2; ++ib) {
            unsigned xa0 = (unsigned)__shfl((int)w0[ib][2 * ks], srcA, 64);
            unsigned xa1 = (unsigned)__shfl((int)w0[ib][2 * ks + 1], srcA, 64);
            unsigned xb0 = (unsigned)__shfl((int)w1[ib][2 * ks], srcA, 64);
            unsigned xb1 = (unsigned)__shfl((int)w1[ib][2 * ks + 1], srcA, 64);
            unsigned xc0 = (unsigned)__shfl((int)w0[ib][2 * ks], srcB, 64);
            unsigned xc1 = (unsigned)__shfl((int)w0[ib][2 * ks + 1], srcB, 64);
            unsigned xd0 = (unsigned)__shfl((int)w1[ib][2 * ks], srcB, 64);
            unsigned xd1 = (unsigned)__shfl((int)w1[ib][2 * ks + 1], srcB, 64);
            uint4 bfv;
            bfv.x = hi ? xa1 : xa0;
            bfv.y = hi ? xb1 : xb0;
            bfv.z = hi ? xc1 : xc0;
            bfv.w = hi ? xd1 : xd0;
            short8 pb = u4s8(bfv);
#pragma unroll
            for (int db = 0; db < 2; ++db) o[db][ib] = MFMA(vt[db], pb, o[db][ib], 0, 0, 0);
        }
    }

    bf16* eb = &EpiB[w][0];
#pragma unroll
    for (int db = 0; db < 2; ++db)
#pragma unroll
        for (int ib = 0; ib < 2; ++ib)
#pragma unroll
            for (int r = 0; r < 4; ++r) {
                int d = db * 16 + lg * 4 + r;
                int il = ib * 16 + lr;
                eb[il * 40 + d] = __float2bfloat16(o[db][ib][r] * rs[ib]);
            }
    int il2 = l >> 1, hf = l & 1;
    uint4 oa = *reinterpret_cast<const uint4*>(&eb[il2 * 40 + hf * 16]);
    uint4 ob2 = *reinterpret_cast<const uint4*>(&eb[il2 * 40 + hf * 16 + 8]);
    size_t gbase = ((size_t)win * 128 + i0 + il2) * 384 + 192 + h * 32 + hf * 16;
    *reinterpret_cast<uint4*>(Ob + gbase) = oa;
    *reinterpret_cast<uint4*>(Ob + gbase + 8) = ob2;
}

// ---------------- MFMA mutual attention (half-grid: b2 passed in) ------------
__global__ __launch_bounds__(256) void attn_mut(
    const bf16* __restrict__ Qb, const bf16* __restrict__ mskF, bf16* __restrict__ Ob,
    int b2) {
    __shared__ __align__(16) bf16 VtB[4096];
    __shared__ __align__(16) bf16 EpiB[4][1280];
    int bid = blockIdx.x;
    int lin = (bid & 7) * 384 + (bid >> 3);         // 3072 blocks
    int widx = lin / 6, h = lin - widx * 6;
    int win = b2 * 512 + widx;
    int tid = threadIdx.x, w = tid >> 6, l = tid & 63;
    int lr = l & 15, lg = l >> 4;
    const float qscale = 0.17677669529663689f;
    size_t qbase = (size_t)widx * 128 * 576 + h * 32;   // local to this half's Q2

#pragma unroll
    for (int it = 0; it < 16; ++it) {
        int idx = it * 256 + tid;
        int d = idx & 31, j = idx >> 5;
        bf16 v = Qb[qbase + (size_t)j * 576 + 384 + d];
        VtB[(d * 256 + (((j >> 3) ^ (d & 7)) << 4) + (j & 7) * 2) >> 1] = v;
    }

    int i0 = w * 32;
    int qoff = (w < 2) ? 64 : -64;
    int koff = (w < 2) ? 0 : 64;
    uint4 kf[4], qf[2];
#pragma unroll
    for (int jb = 0; jb < 4; ++jb)
        kf[jb] = *reinterpret_cast<const uint4*>(
            Qb + qbase + (size_t)(koff + jb * 16 + lr) * 576 + 192 + lg * 8);
#pragma unroll
    for (int ib = 0; ib < 2; ++ib)
        qf[ib] = *reinterpret_cast<const uint4*>(
            Qb + qbase + (size_t)(i0 + ib * 16 + lr + qoff) * 576 + lg * 8);
    f32x4 s[4][2] = {};
#pragma unroll
    for (int jb = 0; jb < 4; ++jb)
#pragma unroll
        for (int ib = 0; ib < 2; ++ib)
            s[jb][ib] = MFMA(u4s8(kf[jb]), u4s8(qf[ib]), s[jb][ib], 0, 0, 0);

    const bf16* mpF = mskF + (size_t)widx * 16384;
    int ibase = (i0 & 63);
#pragma unroll
    for (int jb = 0; jb < 4; ++jb) {
        int jq0 = jb * 4 + lg;
#pragma unroll
        for (int ib = 0; ib < 2; ++ib) {
            int il = ibase + ib * 16 + lr;
            uint2 mv = *reinterpret_cast<const uint2*>(mpF + (jq0 * 128 + il) * 4);
            s[jb][ib][0] = fmaf(s[jb][ib][0], qscale, u2f(mv.x & 0xffffu));
            s[jb][ib][1] = fmaf(s[jb][ib][1], qscale, u2f(mv.x >> 16));
            s[jb][ib][2] = fmaf(s[jb][ib][2], qscale, u2f(mv.y & 0xffffu));
            s[jb][ib][3] = fmaf(s[jb][ib][3], qscale, u2f(mv.y >> 16));
        }
    }

    float rs[2];
    unsigned w0[2][4], w1[2][4];
#pragma unroll
    for (int ib = 0; ib < 2; ++ib) {
        float mx = -1e30f;
#pragma unroll
        for (int jb = 0; jb < 4; ++jb)
#pragma unroll
            for (int r = 0; r < 4; ++r) mx = fmaxf(mx, s[jb][ib][r]);
        mx = fmaxf(mx, __shfl_xor(mx, 16));
        mx = fmaxf(mx, __shfl_xor(mx, 32));
        float sum = 0.0f;
#pragma unroll
        for (int jb = 0; jb < 4; ++jb)
#pragma unroll
            for (int r = 0; r < 4; ++r) {
                float e = __expf(s[jb][ib][r] - mx);
                s[jb][ib][r] = e;
                sum += e;
            }
        sum += __shfl_xor(sum, 16);
        sum += __shfl_xor(sum, 32);
        rs[ib] = 1.0f / sum;
#pragma unroll
        for (int jb = 0; jb < 4; ++jb) {
            w0[ib][jb] = pkbf(s[jb][ib][0], s[jb][ib][1]);
            w1[ib][jb] = pkbf(s[jb][ib][2], s[jb][ib][3]);
        }
    }
    __syncthreads();

    f32x4 o[2][2] = {};
    int srcA = lr + 16 * (2 * (lg & 1));
    int srcB = srcA + 16;
    bool hi = ((lg >> 1) & 1) != 0;
    int gb0 = koff >> 3;
#pragma unroll
    for (int ks = 0; ks < 2; ++ks) {
        short8 vt[2];
#pragma unroll
        for (int db = 0; db < 2; ++db) {
            int d = db * 16 + lr;
            vt[db] = *reinterpret_cast<const short8*>(
                &VtB[(d * 256 + (((gb0 + ks * 4 + lg) ^ (d & 7)) << 4)) >> 1]);
        }
#pragma unroll
        for (int ib = 0; ib < 2; ++ib) {
            unsigned xa0 = (unsigned)__shfl((int)w0[ib][2 * ks], srcA, 64);
            unsigned xa1 = (unsigned)__shfl((int)w0[ib][2 * ks + 1], srcA, 64);
            unsigned xb0 = (unsigned)__shfl((int)w1[ib][2 * ks], srcA, 64);
            unsigned xb1 = (unsigned)__shfl((int)w1[ib][2 * ks + 1], srcA, 64);
            unsigned xc0 = (unsigned)__shfl((int)w0[ib][2 * ks], srcB, 64);
            unsigned xc1 = (unsigned)__shfl((int)w0[ib][2 * ks + 1], srcB, 64);
            unsigned xd0 = (unsigned)__shfl((int)w1[ib][2 * ks], srcB, 64);
            unsigned xd1 = (unsigned)__shfl((int)w1[ib][2 * ks + 1], srcB, 64);
            uint4 bfv;
            bfv.x = hi ? xa1 : xa0;
            bfv.y = hi ? xb1 : xb0;
            bfv.z = hi ? xc1 : xc0;
            bfv.w = hi ? xd1 : xd0;
            short8 pb = u4s8(bfv);
#pragma unroll
            for (int db = 0; db < 2; ++db) o[db][ib] = MFMA(vt[db], pb, o[db][ib], 0, 0, 0);
        }
    }

    bf16* eb = &EpiB[w][0];
#pragma unroll
    for (int db = 0; db < 2; ++db)
#pragma unroll
        for (int ib = 0; ib < 2; ++ib)
#pragma unroll
            for (int r = 0; r < 4; ++r) {
                int d = db * 16 + lg * 4 + r;
                int il = ib * 16 + lr;
                eb[il * 40 + d] = __float2bfloat16(o[db][ib][r] * rs[ib]);
            }
    int il2 = l >> 1, hf = l & 1;
    uint4 oa = *reinterpret_cast<const uint4*>(&eb[il2 * 40 + hf * 16]);
    uint4 ob2 = *reinterpret_cast<const uint4*>(&eb[il2 * 40 + hf * 16 + 8]);
    size_t gbase = ((size_t)win * 128 + i0 + il2) * 384 + h * 32 + hf * 16;
    *reinterpret_cast<uint4*>(Ob + gbase) = oa;
    *reinterpret_cast<uint4*>(Ob + gbase + 8) = ob2;
}

// ---------------------------------------------------------------------------
extern "C" void kernel_launch(void* const* d_in, const int* in_sizes, int n_in,
                              void* d_out, int out_size, void* d_ws, size_t ws_size,
                              hipStream_t stream) {
    const float* x    = (const float*)d_in[0];
    const float* mask = (const float*)d_in[1];
    const float* n1w  = (const float*)d_in[2];
    const float* n1b  = (const float*)d_in[3];
    const float* wqs  = (const float*)d_in[4];
    const float* bqs  = (const float*)d_in[5];
    const float* wqm  = (const float*)d_in[6];
    const float* bqm  = (const float*)d_in[7];
    const float* rpbt = (const float*)d_in[8];
    const float* wproj= (const float*)d_in[9];
    const float* bproj= (const float*)d_in[10];
    const float* n2w  = (const float*)d_in[11];
    const float* n2b  = (const float*)d_in[12];
    const float* w11  = (const float*)d_in[13];
    const float* b11  = (const float*)d_in[14];
    const float* w12  = (const float*)d_in[15];
    const float* b12  = (const float*)d_in[16];
    const float* w2   = (const float*)d_in[17];
    const float* b2   = (const float*)d_in[18];

    char* ws = (char*)d_ws;
    bf16*  A    = (bf16*)(ws + A_OFF);
    bf16*  Q    = (bf16*)(ws + Q_OFF);
    bf16*  O    = (bf16*)(ws + O_OFF);
    float* pos  = (float*)(ws + POS_OFF);
    float* PB   = (float*)(ws + PB_OFF);
    bf16*  rpbF = (bf16*)(ws + RPBF_OFF);
    bf16*  mskF = (bf16*)(ws + MSKF_OFF);
    bf16*  WB   = (bf16*)(ws + WB_OFF);
    bf16*  Hb = A;               // reuse: A dead after dual qkv
    bf16*  G  = Q;               // reuse: Q dead after attention
    float* R  = (float*)d_out;
    float* out = (float*)d_out;
    // Q2 scratch for mutual QKV: d_out region (100.7 MB) is dead until proj
    // overwrites all of R. Per-half mutual QKV needs 65536*576*2B = 75.5 MB.
    bf16*  Q2 = (bf16*)d_out;

    cvtw_kernel<<<(WTOT + 255) / 256, 256, 0, stream>>>(wqs, wqm, wproj, w11, w12, w2, WB);
    pos_kernel<<<96, 256, 0, stream>>>(pos);
    pbias_kernel<<<288, 256, 0, stream>>>(pos, WB + WQM_E, bqm, PB);
    rpbF_kernel<<<384, 256, 0, stream>>>(rpbt, rpbF);
    mskF_kernel<<<8192, 256, 0, stream>>>(mask, mskF);
    ln_kernel<1><<<32768, 256, 0, stream>>>(x, n1w, n1b, A);

    // fused self+mutual qkv, token-halved so Q2 fits in the d_out scratch
    for (int hf = 0; hf < 2; ++hf) {
        const bf16* Ah = A + (size_t)hf * 65536 * 192;
        bf16* Qh = Q + (size_t)hf * 65536 * 576;
        mgemm<5, 0><<<9 * 512, 256, 0, stream>>>(Ah, 192, 9, WB + WQS_E, bqs, WB + WQM_E,
                                                 nullptr, PB, Qh, Q2);
        attn_self<<<3072, 256, 0, stream>>>(Qh, rpbF, mskF, O, hf);
        attn_mut<<<3072, 256, 0, stream>>>(Q2, mskF, O, hf);
    }

    // proj + window-reverse + roll + residual (fully overwrites R = d_out)
    mgemm<2, 0><<<3 * 1024, 256, 0, stream>>>(O, 384, 3, WB + WPR_E, bproj, nullptr, nullptr,
                                              x, R, nullptr);
    ln_kernel<0><<<32768, 256, 0, stream>>>(R, n2w, n2b, Hb);
    // fc11 + fc12 + gelu gate
    mgemm<3, 0><<<6 * 1024, 256, 0, stream>>>(Hb, 192, 6, WB + W11_E, b11, WB + W12_E, b12,
                                              nullptr, G, nullptr);
    // fc2 + final residual
    mgemm<4, 0><<<3 * 1024, 256, 0, stream>>>(G, 384, 3, WB + W2_E, b2, nullptr, nullptr,
                                              R, out, nullptr);
}